// Round 4
// baseline (11.650 us; speedup 1.0000x reference)
//
#include <hip/hip_runtime.h>

#define CANVAS 512
#define NSEG 63

typedef float f2 __attribute__((ext_vector_type(2)));

__device__ __forceinline__ float rdlane(float v, int s) {
    return __int_as_float(__builtin_amdgcn_readlane(__float_as_int(v), s));
}

__global__ __launch_bounds__(256) void diff_path_render(
    const float* __restrict__ traj,      // (64,2) normalized
    const float* __restrict__ thickness, // scalar, pixels
    float* __restrict__ out)             // (512,512)
{
    const int tid  = threadIdx.x;
    const int lane = tid & 63;

    const int bId   = blockIdx.x;        // 0..255 -> 16x16 grid of 32x32 tiles
    const int tileX = (bId & 15) << 5;
    const int tileY = (bId >> 4) << 5;

    const int qc = tid & 15;             // quad col 0..15  (32 px wide)
    const int qr = tid >> 4;             // quad row 0..15  (32 px tall)
    const int c0 = tileX + qc * 2;
    const int r0 = tileY + qr * 2;

    const float INV_S = 1.0f / 512.0f;
    const float EPS   = 1e-5f / (512.0f * 512.0f);  // ref eps in px^2, rescaled

    const float radius = thickness[0] * 0.5f;        // pixels
    const float rn = radius * INV_S;                 // normalized
    const float r2 = rn * rn;

    // ---- phase 1: lane s culls segment s against this wave's 32x8 tile ----
    const int  w   = tid >> 6;                       // wave in block, 0..3
    const float wx0 = (float)tileX * INV_S;
    const float wx1 = (float)(tileX + 31) * INV_S;
    const float wy0 = (float)(tileY + w * 8) * INV_S;
    const float wy1 = (float)(tileY + w * 8 + 7) * INV_S;

    const int si = (lane < NSEG) ? lane : (NSEG - 1);
    const float ax = traj[2 * si + 0];
    const float ay = traj[2 * si + 1];
    const float bx = traj[2 * si + 2];
    const float by = traj[2 * si + 3];

    const float ddx = fmaxf(0.0f, fmaxf(fminf(ax, bx) - wx1, wx0 - fmaxf(ax, bx)));
    const float ddy = fmaxf(0.0f, fmaxf(fminf(ay, by) - wy1, wy0 - fmaxf(ay, by)));
    const float bnd2 = fmaf(ddx, ddx, ddy * ddy);
    unsigned long long mask = __ballot((lane < NSEG) && (bnd2 <= r2));

    const float segx = bx - ax, segy = by - ay;
    const float inv  = __builtin_amdgcn_rcpf(fmaf(segx, segx, fmaf(segy, segy, EPS)));

    // ---- per-quad constants ----
    const f2 px = { (float)c0 * INV_S, (float)(c0 + 1) * INV_S };
    const float py0 = (float)r0 * INV_S;
    const float py1 = py0 + INV_S;

    // min-d^2 initialized to radius^2: any farther segment yields darkness 0,
    // identical to the reference's clip() — culled segments can't change output.
    f2 m0 = { r2, r2 };
    f2 m1 = { r2, r2 };

    // ---- phase 2: evaluate only surviving segments (mask is wave-uniform) ----
    while (mask) {
        const int s = (int)__builtin_ctzll(mask);
        mask &= mask - 1;

        const float sax = rdlane(ax, s),   say = rdlane(ay, s);
        const float ssx = rdlane(segx, s), ssy = rdlane(segy, s);
        const float sinv = rdlane(inv, s);

        const f2 sxv = { ssx, ssx }, syv = { ssy, ssy };
        const f2 dx  = px - (f2){ sax, sax };
        const float dy0 = py0 - say, dy1 = py1 - say;

        f2 t0 = __builtin_elementwise_fma(dx, sxv, (f2){ dy0 * ssy, dy0 * ssy }) * (f2){ sinv, sinv };
        f2 t1 = __builtin_elementwise_fma(dx, sxv, (f2){ dy1 * ssy, dy1 * ssy }) * (f2){ sinv, sinv };
        const f2 zero = { 0.0f, 0.0f }, one = { 1.0f, 1.0f };
        t0 = __builtin_elementwise_min(__builtin_elementwise_max(t0, zero), one);
        t1 = __builtin_elementwise_min(__builtin_elementwise_max(t1, zero), one);

        const f2 qx0 = __builtin_elementwise_fma(-t0, sxv, dx);
        const f2 qx1 = __builtin_elementwise_fma(-t1, sxv, dx);
        const f2 qy0 = __builtin_elementwise_fma(-t0, syv, (f2){ dy0, dy0 });
        const f2 qy1 = __builtin_elementwise_fma(-t1, syv, (f2){ dy1, dy1 });

        const f2 dd0 = __builtin_elementwise_fma(qx0, qx0, qy0 * qy0);
        const f2 dd1 = __builtin_elementwise_fma(qx1, qx1, qy1 * qy1);
        m0 = __builtin_elementwise_min(m0, dd0);
        m1 = __builtin_elementwise_min(m1, dd1);
    }

    // ---- epilogue: darkness + store ----
    const float rinv = __builtin_amdgcn_rcpf(radius);
    float2 o0, o1;
    o0.x = fminf(fmaxf((radius - 512.0f * sqrtf(m0.x)) * rinv, 0.0f), 1.0f);
    o0.y = fminf(fmaxf((radius - 512.0f * sqrtf(m0.y)) * rinv, 0.0f), 1.0f);
    o1.x = fminf(fmaxf((radius - 512.0f * sqrtf(m1.x)) * rinv, 0.0f), 1.0f);
    o1.y = fminf(fmaxf((radius - 512.0f * sqrtf(m1.y)) * rinv, 0.0f), 1.0f);

    *reinterpret_cast<float2*>(out + r0 * CANVAS + c0)       = o0;
    *reinterpret_cast<float2*>(out + (r0 + 1) * CANVAS + c0) = o1;
}

extern "C" void kernel_launch(void* const* d_in, const int* in_sizes, int n_in,
                              void* d_out, int out_size, void* d_ws, size_t ws_size,
                              hipStream_t stream) {
    const float* traj      = (const float*)d_in[0];
    const float* thickness = (const float*)d_in[1];
    float* out = (float*)d_out;

    diff_path_render<<<256, 256, 0, stream>>>(traj, thickness, out);
}

// Round 5
// 11.152 us; speedup vs baseline: 1.0446x; 1.0446x over previous
//
#include <hip/hip_runtime.h>

#define CANVAS 512
#define NPTS 64
#define NSEG (NPTS - 1)

typedef float f2 __attribute__((ext_vector_type(2)));

__global__ __launch_bounds__(256) void diff_path_render(
    const float* __restrict__ traj,      // (64,2) normalized
    const float* __restrict__ thickness, // scalar
    float* __restrict__ out)             // (512,512)
{
    const int t = blockIdx.x * blockDim.x + threadIdx.x;   // 0..65535
    const int pix0 = t * 4;              // four consecutive pixels, one row
    const int row  = pix0 >> 9;
    const int col0 = pix0 & (CANVAS - 1);

    const float INV_S = 1.0f / 512.0f;
    const float py = (float)row * INV_S;
    const f2 px01 = { (float)(col0 + 0) * INV_S, (float)(col0 + 1) * INV_S };
    const f2 px23 = { (float)(col0 + 2) * INV_S, (float)(col0 + 3) * INV_S };
    // reference adds 1e-5 to d2 in PIXEL units; normalized units scale by 512^2
    const float EPS = 1e-5f / (512.0f * 512.0f);

    f2 m01 = { 1e30f, 1e30f };
    f2 m23 = { 1e30f, 1e30f };

    float ax = traj[0], ay = traj[1];    // wave-uniform rolling segment start
#pragma unroll 9
    for (int s = 0; s < NSEG; ++s) {
        float bx = traj[2 * s + 2];
        float by = traj[2 * s + 3];
        float segx = bx - ax, segy = by - ay;
        float d2  = fmaf(segx, segx, fmaf(segy, segy, EPS));
        float inv = __builtin_amdgcn_rcpf(d2);

        float dy   = py - ay;            // per-thread (row) scalar
        float dysy = dy * segy;

        const f2 segxv = { segx, segx };
        const f2 segyv = { segy, segy };
        const f2 dysyv = { dysy, dysy };
        const f2 axv   = { ax, ax };
        const f2 invv  = { inv, inv };
        const f2 zero  = { 0.0f, 0.0f };
        const f2 one   = { 1.0f, 1.0f };

        f2 dx01 = px01 - axv;                                    // v_pk_add
        f2 dx23 = px23 - axv;
        f2 t01 = __builtin_elementwise_fma(dx01, segxv, dysyv);  // v_pk_fma
        f2 t23 = __builtin_elementwise_fma(dx23, segxv, dysyv);
        t01 = t01 * invv;                                        // v_pk_mul
        t23 = t23 * invv;
        t01 = __builtin_elementwise_min(__builtin_elementwise_max(t01, zero), one);
        t23 = __builtin_elementwise_min(__builtin_elementwise_max(t23, zero), one);

        f2 qx01 = __builtin_elementwise_fma(-t01, segxv, dx01);
        f2 qx23 = __builtin_elementwise_fma(-t23, segxv, dx23);
        f2 dyv  = { dy, dy };
        f2 qy01 = __builtin_elementwise_fma(-t01, segyv, dyv);
        f2 qy23 = __builtin_elementwise_fma(-t23, segyv, dyv);

        f2 dd01 = __builtin_elementwise_fma(qx01, qx01, qy01 * qy01);
        f2 dd23 = __builtin_elementwise_fma(qx23, qx23, qy23 * qy23);
        m01 = __builtin_elementwise_min(m01, dd01);
        m23 = __builtin_elementwise_min(m23, dd23);

        ax = bx; ay = by;
    }

    const float radius = thickness[0] * 0.5f;
    const float rinv = __builtin_amdgcn_rcpf(radius);

    float4 o;
    o.x = fminf(fmaxf((radius - 512.0f * sqrtf(m01.x)) * rinv, 0.0f), 1.0f);
    o.y = fminf(fmaxf((radius - 512.0f * sqrtf(m01.y)) * rinv, 0.0f), 1.0f);
    o.z = fminf(fmaxf((radius - 512.0f * sqrtf(m23.x)) * rinv, 0.0f), 1.0f);
    o.w = fminf(fmaxf((radius - 512.0f * sqrtf(m23.y)) * rinv, 0.0f), 1.0f);

    *reinterpret_cast<float4*>(out + pix0) = o;
}

extern "C" void kernel_launch(void* const* d_in, const int* in_sizes, int n_in,
                              void* d_out, int out_size, void* d_ws, size_t ws_size,
                              hipStream_t stream) {
    const float* traj      = (const float*)d_in[0];
    const float* thickness = (const float*)d_in[1];
    float* out = (float*)d_out;

    const int threads = CANVAS * CANVAS / 4;  // 65536 threads, 4 px each
    const int block = 256;
    const int grid = threads / block;         // 256 blocks
    diff_path_render<<<grid, block, 0, stream>>>(traj, thickness, out);
}